// Round 1
// baseline (2201.819 us; speedup 1.0000x reference)
//
#include <hip/hip_runtime.h>
#include <hip/hip_bf16.h>

typedef unsigned short u16;
typedef unsigned int   u32;
typedef __attribute__((ext_vector_type(8))) short bf16x8;
typedef __attribute__((ext_vector_type(4))) float f32x4;

#define HDIM 128
#define TSTEPS 12
#define OUTD 64

__device__ __forceinline__ float bfu(u32 lo16) {
  union { u32 u; float f; } v; v.u = lo16 << 16; return v.f;
}
__device__ __forceinline__ u16 f2bf(float x) {
  union { float f; u32 u; } v; v.f = x;
  return (u16)((v.u + 0x7fffu + ((v.u >> 16) & 1u)) >> 16);
}
__device__ __forceinline__ float sigm(float x) { return 1.0f / (1.0f + __expf(-x)); }
__device__ __forceinline__ float tanh_f(float x) { return 1.0f - 2.0f / (__expf(2.0f * x) + 1.0f); }

// ---------------- setup kernels ----------------

__global__ void k_init(float* c0, float* c1, u16* h0, u16* h1,
                       float* deg, int* cnt, int* cursor, int N) {
  int i = blockIdx.x * 256 + threadIdx.x;
  int nh = N * HDIM;
  if (i < nh) { c0[i] = 0.f; c1[i] = 0.f; h0[i] = 0; h1[i] = 0; }
  if (i < N) { deg[i] = 1.0f; cnt[i] = 0; cursor[i] = 0; }  // deg starts at 1 (self-loop w=1)
}

// x (N,128,12) f32 -> xb (12,N,128) bf16
__global__ void k_xpose(const float* __restrict__ x, u16* __restrict__ xb, int N) {
  int i = blockIdx.x * 256 + threadIdx.x;  // (n,f)
  if (i >= N * HDIM) return;
  const float* src = x + (size_t)i * 12;
  float4 a = *(const float4*)src;
  float4 b = *(const float4*)(src + 4);
  float4 c = *(const float4*)(src + 8);
  float v[12] = { a.x,a.y,a.z,a.w,b.x,b.y,b.z,b.w,c.x,c.y,c.z,c.w };
#pragma unroll
  for (int t = 0; t < 12; ++t) xb[(size_t)t * N * HDIM + i] = f2bf(v[t]);
}

__global__ void k_deg(const int* __restrict__ ei, const float* __restrict__ ea,
                      float* deg, int* cnt, int E) {
  int e = blockIdx.x * 256 + threadIdx.x;
  if (e >= E) return;
  int col = ei[E + e];
  atomicAdd(&deg[col], ea[e * 4 + 3]);
  atomicAdd(&cnt[col], 1);
}

__global__ void k_node(const float* __restrict__ deg, float* dis, float* selfn, int N) {
  int j = blockIdx.x * 256 + threadIdx.x;
  if (j >= N) return;
  float d = deg[j];
  float r = (d > 0.f) ? rsqrtf(d) : 0.f;
  dis[j] = r; selfn[j] = r * r;
}

__global__ void k_scan(const int* __restrict__ cnt, int* __restrict__ rp, int n) {
  __shared__ int sums[1024];
  int tid = threadIdx.x;
  int chunk = (n + 1023) / 1024;
  int start = tid * chunk;
  int end = start + chunk; if (end > n) end = n;
  int s = 0;
  for (int i = start; i < end; ++i) s += cnt[i];
  sums[tid] = s;
  __syncthreads();
  for (int off = 1; off < 1024; off <<= 1) {
    int v = (tid >= off) ? sums[tid - off] : 0;
    __syncthreads();
    sums[tid] += v;
    __syncthreads();
  }
  int run = (tid == 0) ? 0 : sums[tid - 1];
  for (int i = start; i < end; ++i) { rp[i] = run; run += cnt[i]; }
  if (tid == 1023) rp[n] = sums[1023];
}

__global__ void k_scatter(const int* __restrict__ ei, const float* __restrict__ ea,
                          const float* __restrict__ dis, const int* __restrict__ rp,
                          int* cursor, int* esrc, float* enrm, int E) {
  int e = blockIdx.x * 256 + threadIdx.x;
  if (e >= E) return;
  int row = ei[e], col = ei[E + e];
  int pos = atomicAdd(&cursor[col], 1);
  int idx = rp[col] + pos;
  esrc[idx] = row;
  enrm[idx] = dis[row] * ea[e * 4 + 3] * dis[col];
}

// src (K,J) f32 row-major -> dst[j*ldK + k] bf16 (transposed)
__global__ void k_wt(const float* __restrict__ src, u16* __restrict__ dst, int K, int J, int ldK) {
  int idx = blockIdx.x * 256 + threadIdx.x;
  if (idx >= K * J) return;
  int k = idx / J, j = idx % J;
  dst[j * ldK + k] = f2bf(src[idx]);
}

__global__ void k_bias4(const float* f, const float* i_, const float* o, const float* c, float* dst) {
  int t = blockIdx.x * 256 + threadIdx.x;
  if (t >= 512) return;
  const float* p[4] = { f, i_, o, c };
  dst[t] = p[t >> 7][t & 127];
}

// ---------------- MFMA GEMM (NT): C[M,NC] = A[M,KT] * Wt[NC,KT]^T ----------------
// A given as up to 3 segments of width 128 (column blocks). BM=BN=128, BK=32.
__global__ __launch_bounds__(256)
void k_gemm(const u16* __restrict__ seg0, const u16* __restrict__ seg1,
            const u16* __restrict__ seg2, const u16* __restrict__ wt,
            const float* __restrict__ bias, float* __restrict__ Cf,
            u16* __restrict__ Cb, int M, int NC, int KT) {
  __shared__ short lA[128 * 40];
  __shared__ short lB[128 * 40];
  const u16* segs[3] = { seg0, seg1, seg2 };
  const int tid = threadIdx.x;
  const int row0 = blockIdx.x * 128;
  const int col0 = blockIdx.y * 128;
  const int wave = tid >> 6, lane = tid & 63;
  const int wm = (wave >> 1) * 64, wn = (wave & 1) * 64;
  const int lr = tid >> 2, lc = (tid & 3) * 8;
  const int fr = lane & 15, fk = (lane >> 4) * 8;

  f32x4 acc[4][4] = {};

  int r1 = row0 + lr;      if (r1 > M - 1) r1 = M - 1;
  int r2 = row0 + lr + 64; if (r2 > M - 1) r2 = M - 1;
  const int n1 = col0 + lr, n2 = n1 + 64;

  for (int k0 = 0; k0 < KT; k0 += 32) {
    const u16* As = segs[k0 >> 7];
    const int sk = (k0 & 127) + lc;
    *(int4*)&lA[lr * 40 + lc]        = *(const int4*)&As[(size_t)r1 * HDIM + sk];
    *(int4*)&lA[(lr + 64) * 40 + lc] = *(const int4*)&As[(size_t)r2 * HDIM + sk];
    *(int4*)&lB[lr * 40 + lc]        = *(const int4*)&wt[(size_t)n1 * KT + k0 + lc];
    *(int4*)&lB[(lr + 64) * 40 + lc] = *(const int4*)&wt[(size_t)n2 * KT + k0 + lc];
    __syncthreads();
    bf16x8 af[4], bfr[4];
#pragma unroll
    for (int m = 0; m < 4; ++m) af[m]  = *(const bf16x8*)&lA[(wm + m * 16 + fr) * 40 + fk];
#pragma unroll
    for (int n = 0; n < 4; ++n) bfr[n] = *(const bf16x8*)&lB[(wn + n * 16 + fr) * 40 + fk];
#pragma unroll
    for (int m = 0; m < 4; ++m)
#pragma unroll
      for (int n = 0; n < 4; ++n)
        acc[m][n] = __builtin_amdgcn_mfma_f32_16x16x32_bf16(af[m], bfr[n], acc[m][n], 0, 0, 0);
    __syncthreads();
  }

  const int fq4 = (lane >> 4) * 4;
#pragma unroll
  for (int m = 0; m < 4; ++m) {
#pragma unroll
    for (int n = 0; n < 4; ++n) {
      const int colg = col0 + wn + n * 16 + fr;
      const float bv = bias ? bias[colg] : 0.0f;
#pragma unroll
      for (int i = 0; i < 4; ++i) {
        const int rowg = row0 + wm + m * 16 + fq4 + i;
        if (rowg < M) {
          float val = acc[m][n][i] + bv;
          if (Cf) Cf[(size_t)rowg * NC + colg] = val;
          else    Cb[(size_t)rowg * NC + colg] = f2bf(val);
        }
      }
    }
  }
}

// ---------------- CSR gather aggregation + sigmoid -> g (bf16) ----------------
__global__ void k_agg(const u16* __restrict__ xw, const int* __restrict__ rp,
                      const int* __restrict__ esrc, const float* __restrict__ enrm,
                      const float* __restrict__ selfn, const float* __restrict__ gb,
                      u16* __restrict__ g, int N) {
  __shared__ int   s_src[64];
  __shared__ float s_nrm[64];
  int j = blockIdx.x;
  int lane = threadIdx.x;  // 64
  int beg = rp[j], end = rp[j + 1];
  float sn = selfn[j];
  u32 v = *(const u32*)(xw + (size_t)j * HDIM + lane * 2);
  float a0 = sn * bfu(v & 0xffffu);
  float a1 = sn * bfu(v >> 16);
  for (int cb = beg; cb < end; cb += 64) {
    int m = end - cb; if (m > 64) m = 64;
    if (lane < m) { s_src[lane] = esrc[cb + lane]; s_nrm[lane] = enrm[cb + lane]; }
    __syncthreads();
    for (int e = 0; e < m; ++e) {
      int sr = s_src[e]; float w = s_nrm[e];
      u32 vv = *(const u32*)(xw + (size_t)sr * HDIM + lane * 2);
      a0 += w * bfu(vv & 0xffffu);
      a1 += w * bfu(vv >> 16);
    }
    __syncthreads();
  }
  a0 = sigm(a0 + gb[lane * 2]);
  a1 = sigm(a1 + gb[lane * 2 + 1]);
  u32 outp = ((u32)f2bf(a1) << 16) | (u32)f2bf(a0);
  *(u32*)(g + (size_t)j * HDIM + lane * 2) = outp;
}

// ---------------- LSTM cell elementwise ----------------
__global__ void k_cell(const float* __restrict__ gates, float* __restrict__ c,
                       u16* __restrict__ h, int total) {
  int i = blockIdx.x * 256 + threadIdx.x;
  if (i >= total) return;
  int n = i >> 7, hc = i & 127;
  const float* gr = gates + (size_t)n * 512;
  float f  = sigm(gr[hc]);
  float it = sigm(gr[128 + hc]);
  float o  = sigm(gr[256 + hc]);
  float cd = tanh_f(gr[384 + hc]);
  float cn = f * c[i] + it * cd;
  c[i] = cn;
  h[i] = f2bf(o * tanh_f(cn));
}

// ---------------- output projection: out = h1 @ ow + ob ----------------
__global__ void k_out(const u16* __restrict__ h, const float* __restrict__ ow,
                      const float* __restrict__ ob, float* __restrict__ out, int M) {
  __shared__ float lw[HDIM * OUTD];
  __shared__ float lb[OUTD];
  int tid = threadIdx.x;  // 256
  for (int i = tid; i < HDIM * OUTD; i += 256) lw[i] = ow[i];
  if (tid < OUTD) lb[tid] = ob[tid];
  __syncthreads();
  int j = tid & 63;
  int nl = tid >> 6;
  int n = blockIdx.x * 4 + nl;
  if (n >= M) return;
  const u16* hr = h + (size_t)n * HDIM;
  float s = lb[j];
#pragma unroll 4
  for (int k = 0; k < HDIM; ++k) s += bfu(hr[k]) * lw[k * OUTD + j];
  out[(size_t)n * OUTD + j] = s;
}

// ---------------- host ----------------
extern "C" void kernel_launch(void* const* d_in, const int* in_sizes, int n_in,
                              void* d_out, int out_size, void* d_ws, size_t ws_size,
                              hipStream_t stream) {
  const float* x  = (const float*)d_in[0];
  const float* ea = (const float*)d_in[1];
  const int*   ei = (const int*)d_in[2];
  const float* gw[2] = { (const float*)d_in[3],  (const float*)d_in[13] };
  const float* gb[2] = { (const float*)d_in[4],  (const float*)d_in[14] };
  const float* wg[2][4] = {
    { (const float*)d_in[5],  (const float*)d_in[7],  (const float*)d_in[9],  (const float*)d_in[11] },
    { (const float*)d_in[15], (const float*)d_in[17], (const float*)d_in[19], (const float*)d_in[21] } };
  const float* bg[2][4] = {
    { (const float*)d_in[6],  (const float*)d_in[8],  (const float*)d_in[10], (const float*)d_in[12] },
    { (const float*)d_in[16], (const float*)d_in[18], (const float*)d_in[20], (const float*)d_in[22] } };
  const float* ow = (const float*)d_in[23];
  const float* ob = (const float*)d_in[24];
  float* out = (float*)d_out;

  const int N = in_sizes[0] / (HDIM * TSTEPS);
  const int E = in_sizes[2] / 2;
  const int nh = N * HDIM;

  size_t off = 0;
  auto alloc = [&](size_t bytes) -> void* {
    void* p = (char*)d_ws + off;
    off += (bytes + 255) & ~(size_t)255;
    return p;
  };
  u16* xb = (u16*)alloc((size_t)TSTEPS * nh * 2);
  u16* hb[2]   = { (u16*)alloc((size_t)nh * 2), (u16*)alloc((size_t)nh * 2) };
  u16* gbuf[2] = { (u16*)alloc((size_t)nh * 2), (u16*)alloc((size_t)nh * 2) };
  float* cst[2] = { (float*)alloc((size_t)nh * 4), (float*)alloc((size_t)nh * 4) };
  u16* xw = (u16*)alloc((size_t)nh * 2);
  float* gates = (float*)alloc((size_t)N * 512 * 4);
  float* deg   = (float*)alloc((size_t)N * 4);
  float* dis   = (float*)alloc((size_t)N * 4);
  float* selfn = (float*)alloc((size_t)N * 4);
  int* cnt     = (int*)alloc((size_t)N * 4);
  int* cursor  = (int*)alloc((size_t)N * 4);
  int* rp      = (int*)alloc((size_t)(N + 1) * 4);
  int* esrc    = (int*)alloc((size_t)E * 4);
  float* enrm  = (float*)alloc((size_t)E * 4);
  u16* gwT[2] = { (u16*)alloc(HDIM * HDIM * 2), (u16*)alloc(HDIM * HDIM * 2) };
  u16* w4T[2] = { (u16*)alloc(512 * 384 * 2),   (u16*)alloc(512 * 384 * 2) };
  float* b4[2] = { (float*)alloc(512 * 4), (float*)alloc(512 * 4) };

  k_init<<<(nh + 255) / 256, 256, 0, stream>>>(cst[0], cst[1], hb[0], hb[1], deg, cnt, cursor, N);
  k_xpose<<<(nh + 255) / 256, 256, 0, stream>>>(x, xb, N);
  k_deg<<<(E + 255) / 256, 256, 0, stream>>>(ei, ea, deg, cnt, E);
  k_node<<<(N + 255) / 256, 256, 0, stream>>>(deg, dis, selfn, N);
  k_scan<<<1, 1024, 0, stream>>>(cnt, rp, N);
  k_scatter<<<(E + 255) / 256, 256, 0, stream>>>(ei, ea, dis, rp, cursor, esrc, enrm, E);
  for (int l = 0; l < 2; ++l) {
    k_wt<<<(HDIM * HDIM + 255) / 256, 256, 0, stream>>>(gw[l], gwT[l], HDIM, HDIM, HDIM);
    for (int g = 0; g < 4; ++g)
      k_wt<<<(384 * HDIM + 255) / 256, 256, 0, stream>>>(wg[l][g], w4T[l] + g * HDIM * 384, 384, HDIM, 384);
    k_bias4<<<2, 256, 0, stream>>>(bg[l][0], bg[l][1], bg[l][2], bg[l][3], b4[l]);
  }

  dim3 g1((N + 127) / 128, 1), g4((N + 127) / 128, 4);
  for (int t = 0; t < TSTEPS; ++t) {
    for (int l = 0; l < 2; ++l) {
      const u16* xt = (l == 0) ? (xb + (size_t)t * nh) : hb[0];
      k_gemm<<<g1, 256, 0, stream>>>(xt, xt, xt, gwT[l], nullptr, nullptr, xw, N, HDIM, HDIM);
      k_agg<<<N, 64, 0, stream>>>(xw, rp, esrc, enrm, selfn, gb[l], gbuf[l], N);
      k_gemm<<<g4, 256, 0, stream>>>(xt, gbuf[l], hb[l], w4T[l], b4[l], gates, nullptr, N, 512, 384);
      k_cell<<<(nh + 255) / 256, 256, 0, stream>>>(gates, cst[l], hb[l], nh);
    }
  }
  k_out<<<(N + 3) / 4, 256, 0, stream>>>(hb[1], ow, ob, out, N);
}

// Round 2
// 1806.610 us; speedup vs baseline: 1.2188x; 1.2188x over previous
//
#include <hip/hip_runtime.h>
#include <hip/hip_bf16.h>

typedef unsigned short u16;
typedef unsigned int   u32;
typedef __attribute__((ext_vector_type(8))) short bf16x8;
typedef __attribute__((ext_vector_type(4))) float f32x4;

#define HDIM 128
#define TSTEPS 12
#define OUTD 64

__device__ __forceinline__ float bfu(u32 lo16) {
  union { u32 u; float f; } v; v.u = lo16 << 16; return v.f;
}
__device__ __forceinline__ u16 f2bf(float x) {
  union { float f; u32 u; } v; v.f = x;
  return (u16)((v.u + 0x7fffu + ((v.u >> 16) & 1u)) >> 16);
}
__device__ __forceinline__ float sigm(float x) { return 1.0f / (1.0f + __expf(-x)); }
__device__ __forceinline__ float tanh_f(float x) { return 1.0f - 2.0f / (__expf(2.0f * x) + 1.0f); }

// ---------------- setup kernels ----------------

__global__ void k_init(float* c0, float* c1, u16* h0a, u16* h0b, u16* h1a, u16* h1b,
                       int* cnt, int* cursor, int N) {
  int i = blockIdx.x * 256 + threadIdx.x;
  int nh = N * HDIM;
  if (i < nh) { c0[i] = 0.f; c1[i] = 0.f; h0a[i] = 0; h0b[i] = 0; h1a[i] = 0; h1b[i] = 0; }
  if (i < N) { cnt[i] = 0; cursor[i] = 0; }
}

// x (N,128,12) f32 -> xb (12,N,128) bf16
__global__ void k_xpose(const float* __restrict__ x, u16* __restrict__ xb, int N) {
  int i = blockIdx.x * 256 + threadIdx.x;  // (n,f)
  if (i >= N * HDIM) return;
  const float* src = x + (size_t)i * 12;
  float4 a = *(const float4*)src;
  float4 b = *(const float4*)(src + 4);
  float4 c = *(const float4*)(src + 8);
  float v[12] = { a.x,a.y,a.z,a.w,b.x,b.y,b.z,b.w,c.x,c.y,c.z,c.w };
#pragma unroll
  for (int t = 0; t < 12; ++t) xb[(size_t)t * N * HDIM + i] = f2bf(v[t]);
}

__global__ void k_cnt(const int* __restrict__ ei, int* cnt, int E) {
  int e = blockIdx.x * 256 + threadIdx.x;
  if (e >= E) return;
  atomicAdd(&cnt[ei[E + e]], 1);
}

__global__ void k_scan(const int* __restrict__ cnt, int* __restrict__ rp, int n) {
  __shared__ int sums[1024];
  int tid = threadIdx.x;
  int chunk = (n + 1023) / 1024;
  int start = tid * chunk;
  int end = start + chunk; if (end > n) end = n;
  int s = 0;
  for (int i = start; i < end; ++i) s += cnt[i];
  sums[tid] = s;
  __syncthreads();
  for (int off = 1; off < 1024; off <<= 1) {
    int v = (tid >= off) ? sums[tid - off] : 0;
    __syncthreads();
    sums[tid] += v;
    __syncthreads();
  }
  int run = (tid == 0) ? 0 : sums[tid - 1];
  for (int i = start; i < end; ++i) { rp[i] = run; run += cnt[i]; }
  if (tid == 1023) rp[n] = sums[1023];
}

__global__ void k_scatter(const int* __restrict__ ei, const float* __restrict__ ea,
                          const int* __restrict__ rp, int* cursor,
                          int* esrc, float* ew, int E) {
  int e = blockIdx.x * 256 + threadIdx.x;
  if (e >= E) return;
  int row = ei[e], col = ei[E + e];
  int pos = atomicAdd(&cursor[col], 1);
  int idx = rp[col] + pos;
  esrc[idx] = row;
  ew[idx] = ea[e * 4 + 3];
}

// per-node CSR weight sum -> dis, selfn (no atomics, coalesced)
__global__ void k_degcsr(const int* __restrict__ rp, const float* __restrict__ ew,
                         float* dis, float* selfn, int N) {
  int j = blockIdx.x;
  int lane = threadIdx.x;  // 64
  int beg = rp[j], end = rp[j + 1];
  float s = 0.f;
  for (int i = beg + lane; i < end; i += 64) s += ew[i];
#pragma unroll
  for (int o = 32; o; o >>= 1) s += __shfl_down(s, o);
  if (lane == 0) {
    float d = 1.0f + s;  // self-loop weight 1
    dis[j] = rsqrtf(d);
    selfn[j] = 1.0f / d;
  }
}

__global__ void k_enrm(const int* __restrict__ rp, const int* __restrict__ esrc,
                       const float* __restrict__ dis, float* ew, int N) {
  int j = blockIdx.x;
  int lane = threadIdx.x;  // 64
  int beg = rp[j], end = rp[j + 1];
  float dj = dis[j];
  for (int i = beg + lane; i < end; i += 64) ew[i] = dis[esrc[i]] * ew[i] * dj;
}

// src (K,J) f32 row-major -> dst[j*ldK + k] bf16 (transposed)
__global__ void k_wt(const float* __restrict__ src, u16* __restrict__ dst, int K, int J, int ldK) {
  int idx = blockIdx.x * 256 + threadIdx.x;
  if (idx >= K * J) return;
  int k = idx / J, j = idx % J;
  dst[j * ldK + k] = f2bf(src[idx]);
}

// fused gate weights, column-permuted: p[3:0]=hc_lo, p[5:4]=gate, p[8:6]=hc_hi
__global__ void k_wt4(const float* wf, const float* wi, const float* wo, const float* wc,
                      u16* __restrict__ dst) {
  int idx = blockIdx.x * 256 + threadIdx.x;  // 512*384
  if (idx >= 512 * 384) return;
  int p = idx / 384, k = idx % 384;
  int g = (p >> 4) & 3;
  int hc = (p & 15) | ((p >> 6) << 4);
  const float* w[4] = { wf, wi, wo, wc };
  dst[p * 384 + k] = f2bf(w[g][k * HDIM + hc]);
}

__global__ void k_bias4(const float* bf, const float* bi, const float* bo, const float* bc,
                        float* dst) {
  int p = blockIdx.x * 256 + threadIdx.x;
  if (p >= 512) return;
  int g = (p >> 4) & 3;
  int hc = (p & 15) | ((p >> 6) << 4);
  const float* b[4] = { bf, bi, bo, bc };
  dst[p] = b[g][hc];
}

// ---------------- MFMA GEMM (NT): C[M,128] = A[M,128] * Wt[128,128]^T -> bf16 ----------------
__global__ __launch_bounds__(256)
void k_gemm(const u16* __restrict__ A, const u16* __restrict__ wt,
            u16* __restrict__ Cb, int M) {
  __shared__ short lA[128 * 40];
  __shared__ short lB[128 * 40];
  const int tid = threadIdx.x;
  const int row0 = blockIdx.x * 128;
  const int wave = tid >> 6, lane = tid & 63;
  const int wm = (wave >> 1) * 64, wn = (wave & 1) * 64;
  const int lr = tid >> 2, lc = (tid & 3) * 8;
  const int fr = lane & 15, fk = (lane >> 4) * 8;

  f32x4 acc[4][4] = {};

  int r1 = row0 + lr;      if (r1 > M - 1) r1 = M - 1;
  int r2 = row0 + lr + 64; if (r2 > M - 1) r2 = M - 1;
  const int n1 = lr, n2 = lr + 64;

  for (int k0 = 0; k0 < 128; k0 += 32) {
    const int sk = k0 + lc;
    *(int4*)&lA[lr * 40 + lc]        = *(const int4*)&A[(size_t)r1 * HDIM + sk];
    *(int4*)&lA[(lr + 64) * 40 + lc] = *(const int4*)&A[(size_t)r2 * HDIM + sk];
    *(int4*)&lB[lr * 40 + lc]        = *(const int4*)&wt[(size_t)n1 * HDIM + sk];
    *(int4*)&lB[(lr + 64) * 40 + lc] = *(const int4*)&wt[(size_t)n2 * HDIM + sk];
    __syncthreads();
    bf16x8 af[4], bfr[4];
#pragma unroll
    for (int m = 0; m < 4; ++m) af[m]  = *(const bf16x8*)&lA[(wm + m * 16 + fr) * 40 + fk];
#pragma unroll
    for (int n = 0; n < 4; ++n) bfr[n] = *(const bf16x8*)&lB[(wn + n * 16 + fr) * 40 + fk];
#pragma unroll
    for (int m = 0; m < 4; ++m)
#pragma unroll
      for (int n = 0; n < 4; ++n)
        acc[m][n] = __builtin_amdgcn_mfma_f32_16x16x32_bf16(af[m], bfr[n], acc[m][n], 0, 0, 0);
    __syncthreads();
  }

  const int fq4 = (lane >> 4) * 4;
#pragma unroll
  for (int m = 0; m < 4; ++m)
#pragma unroll
    for (int n = 0; n < 4; ++n) {
      const int colg = wn + n * 16 + fr;
#pragma unroll
      for (int i = 0; i < 4; ++i) {
        const int rowg = row0 + wm + m * 16 + fq4 + i;
        if (rowg < M) Cb[(size_t)rowg * HDIM + colg] = f2bf(acc[m][n][i]);
      }
    }
}

// ------------- fused gates GEMM + LSTM cell epilogue -------------
// A = [seg0|seg1|seg2] (each M x 128 bf16), W = w4T (512 x 384, col-permuted), grid (ceil(M/128), 4)
__global__ __launch_bounds__(256)
void k_gemm_gate(const u16* __restrict__ seg0, const u16* __restrict__ seg1,
                 const u16* __restrict__ seg2, const u16* __restrict__ wt,
                 const float* __restrict__ b4p, float* __restrict__ cst,
                 u16* __restrict__ hout, int M) {
  __shared__ short lA[128 * 40];
  __shared__ short lB[128 * 40];
  const u16* segs[3] = { seg0, seg1, seg2 };
  const int tid = threadIdx.x;
  const int row0 = blockIdx.x * 128;
  const int col0 = blockIdx.y * 128;
  const int wave = tid >> 6, lane = tid & 63;
  const int wm = (wave >> 1) * 64, wn = (wave & 1) * 64;
  const int lr = tid >> 2, lc = (tid & 3) * 8;
  const int fr = lane & 15, fk = (lane >> 4) * 8;

  f32x4 acc[4][4] = {};

  int r1 = row0 + lr;      if (r1 > M - 1) r1 = M - 1;
  int r2 = row0 + lr + 64; if (r2 > M - 1) r2 = M - 1;
  const int n1 = col0 + lr, n2 = n1 + 64;

  for (int k0 = 0; k0 < 384; k0 += 32) {
    const u16* As = segs[k0 >> 7];
    const int sk = (k0 & 127) + lc;
    *(int4*)&lA[lr * 40 + lc]        = *(const int4*)&As[(size_t)r1 * HDIM + sk];
    *(int4*)&lA[(lr + 64) * 40 + lc] = *(const int4*)&As[(size_t)r2 * HDIM + sk];
    *(int4*)&lB[lr * 40 + lc]        = *(const int4*)&wt[(size_t)n1 * 384 + k0 + lc];
    *(int4*)&lB[(lr + 64) * 40 + lc] = *(const int4*)&wt[(size_t)n2 * 384 + k0 + lc];
    __syncthreads();
    bf16x8 af[4], bfr[4];
#pragma unroll
    for (int m = 0; m < 4; ++m) af[m]  = *(const bf16x8*)&lA[(wm + m * 16 + fr) * 40 + fk];
#pragma unroll
    for (int n = 0; n < 4; ++n) bfr[n] = *(const bf16x8*)&lB[(wn + n * 16 + fr) * 40 + fk];
#pragma unroll
    for (int m = 0; m < 4; ++m)
#pragma unroll
      for (int n = 0; n < 4; ++n)
        acc[m][n] = __builtin_amdgcn_mfma_f32_16x16x32_bf16(af[m], bfr[n], acc[m][n], 0, 0, 0);
    __syncthreads();
  }

  // epilogue: lane's 4 n-fragments are gates f,i,o,c of channel hc
  const int fq4 = (lane >> 4) * 4;
  const int hc = fr | ((blockIdx.y * 2 + (wave & 1)) << 4);
  const int colbase = col0 + wn + fr;
  const float bb0 = b4p[colbase];
  const float bb1 = b4p[colbase + 16];
  const float bb2 = b4p[colbase + 32];
  const float bb3 = b4p[colbase + 48];
#pragma unroll
  for (int m = 0; m < 4; ++m)
#pragma unroll
    for (int i = 0; i < 4; ++i) {
      const int rowg = row0 + wm + m * 16 + fq4 + i;
      if (rowg < M) {
        float f_ = sigm(acc[m][0][i] + bb0);
        float i_ = sigm(acc[m][1][i] + bb1);
        float o_ = sigm(acc[m][2][i] + bb2);
        float cd = tanh_f(acc[m][3][i] + bb3);
        size_t idx = (size_t)rowg * HDIM + hc;
        float cn = f_ * cst[idx] + i_ * cd;
        cst[idx] = cn;
        hout[idx] = f2bf(o_ * tanh_f(cn));
      }
    }
}

// ---------------- CSR gather aggregation + sigmoid -> g (bf16) ----------------
// batched: blockIdx.x in [0, B*N); node = bid % N; rows offset by (bid - node)
__global__ void k_agg(const u16* __restrict__ xw, const int* __restrict__ rp,
                      const int* __restrict__ esrc, const float* __restrict__ enrm,
                      const float* __restrict__ selfn, const float* __restrict__ gb,
                      u16* __restrict__ g, int N) {
  __shared__ int   s_src[64];
  __shared__ float s_nrm[64];
  int bid = blockIdx.x;
  int j = bid % N;
  int base = bid - j;
  int lane = threadIdx.x;  // 64
  int beg = rp[j], end = rp[j + 1];
  float sn = selfn[j];
  u32 v = *(const u32*)(xw + (size_t)bid * HDIM + lane * 2);
  float a0 = sn * bfu(v & 0xffffu);
  float a1 = sn * bfu(v >> 16);
  for (int cb = beg; cb < end; cb += 64) {
    int m = end - cb; if (m > 64) m = 64;
    if (lane < m) { s_src[lane] = esrc[cb + lane]; s_nrm[lane] = enrm[cb + lane]; }
    __syncthreads();
    for (int e = 0; e < m; ++e) {
      int sr = base + s_src[e]; float w = s_nrm[e];
      u32 vv = *(const u32*)(xw + (size_t)sr * HDIM + lane * 2);
      a0 += w * bfu(vv & 0xffffu);
      a1 += w * bfu(vv >> 16);
    }
    __syncthreads();
  }
  a0 = sigm(a0 + gb[lane * 2]);
  a1 = sigm(a1 + gb[lane * 2 + 1]);
  u32 outp = ((u32)f2bf(a1) << 16) | (u32)f2bf(a0);
  *(u32*)(g + (size_t)bid * HDIM + lane * 2) = outp;
}

// ---------------- output projection: out = h1 @ ow + ob ----------------
__global__ void k_out(const u16* __restrict__ h, const float* __restrict__ ow,
                      const float* __restrict__ ob, float* __restrict__ out, int M) {
  __shared__ float lw[HDIM * OUTD];
  __shared__ float lb[OUTD];
  int tid = threadIdx.x;  // 256
  for (int i = tid; i < HDIM * OUTD; i += 256) lw[i] = ow[i];
  if (tid < OUTD) lb[tid] = ob[tid];
  __syncthreads();
  int j = tid & 63;
  int nl = tid >> 6;
  int n = blockIdx.x * 4 + nl;
  if (n >= M) return;
  const u16* hr = h + (size_t)n * HDIM;
  float s = lb[j];
#pragma unroll 4
  for (int k = 0; k < HDIM; ++k) s += bfu(hr[k]) * lw[k * OUTD + j];
  out[(size_t)n * OUTD + j] = s;
}

// ---------------- host ----------------
extern "C" void kernel_launch(void* const* d_in, const int* in_sizes, int n_in,
                              void* d_out, int out_size, void* d_ws, size_t ws_size,
                              hipStream_t stream) {
  const float* x  = (const float*)d_in[0];
  const float* ea = (const float*)d_in[1];
  const int*   ei = (const int*)d_in[2];
  const float* gw[2] = { (const float*)d_in[3],  (const float*)d_in[13] };
  const float* gb[2] = { (const float*)d_in[4],  (const float*)d_in[14] };
  const float* wg[2][4] = {
    { (const float*)d_in[5],  (const float*)d_in[7],  (const float*)d_in[9],  (const float*)d_in[11] },
    { (const float*)d_in[15], (const float*)d_in[17], (const float*)d_in[19], (const float*)d_in[21] } };
  const float* bg[2][4] = {
    { (const float*)d_in[6],  (const float*)d_in[8],  (const float*)d_in[10], (const float*)d_in[12] },
    { (const float*)d_in[16], (const float*)d_in[18], (const float*)d_in[20], (const float*)d_in[22] } };
  const float* ow = (const float*)d_in[23];
  const float* ob = (const float*)d_in[24];
  float* out = (float*)d_out;

  const int N = in_sizes[0] / (HDIM * TSTEPS);
  const int E = in_sizes[2] / 2;
  const int nh = N * HDIM;
  const int tnh = TSTEPS * nh;

  size_t off = 0;
  auto alloc = [&](size_t bytes) -> void* {
    void* p = (char*)d_ws + off;
    off += (bytes + 255) & ~(size_t)255;
    return p;
  };
  u16* xb     = (u16*)alloc((size_t)tnh * 2);
  u16* xw_all = (u16*)alloc((size_t)tnh * 2);
  u16* g0_all = (u16*)alloc((size_t)tnh * 2);
  u16* h0A = (u16*)alloc((size_t)nh * 2);
  u16* h0B = (u16*)alloc((size_t)nh * 2);
  u16* h1A = (u16*)alloc((size_t)nh * 2);
  u16* h1B = (u16*)alloc((size_t)nh * 2);
  u16* g1buf = (u16*)alloc((size_t)nh * 2);
  u16* xw1   = (u16*)alloc((size_t)nh * 2);
  float* cst[2] = { (float*)alloc((size_t)nh * 4), (float*)alloc((size_t)nh * 4) };
  float* dis   = (float*)alloc((size_t)N * 4);
  float* selfn = (float*)alloc((size_t)N * 4);
  int* cnt     = (int*)alloc((size_t)N * 4);
  int* cursor  = (int*)alloc((size_t)N * 4);
  int* rp      = (int*)alloc((size_t)(N + 1) * 4);
  int* esrc    = (int*)alloc((size_t)E * 4);
  float* ew    = (float*)alloc((size_t)E * 4);
  u16* gwT[2] = { (u16*)alloc(HDIM * HDIM * 2), (u16*)alloc(HDIM * HDIM * 2) };
  u16* w4T[2] = { (u16*)alloc(512 * 384 * 2),   (u16*)alloc(512 * 384 * 2) };
  float* b4[2] = { (float*)alloc(512 * 4), (float*)alloc(512 * 4) };

  // setup
  k_init<<<(nh + 255) / 256, 256, 0, stream>>>(cst[0], cst[1], h0A, h0B, h1A, h1B, cnt, cursor, N);
  k_xpose<<<(nh + 255) / 256, 256, 0, stream>>>(x, xb, N);
  k_cnt<<<(E + 255) / 256, 256, 0, stream>>>(ei, cnt, E);
  k_scan<<<1, 1024, 0, stream>>>(cnt, rp, N);
  k_scatter<<<(E + 255) / 256, 256, 0, stream>>>(ei, ea, rp, cursor, esrc, ew, E);
  k_degcsr<<<N, 64, 0, stream>>>(rp, ew, dis, selfn, N);
  k_enrm<<<N, 64, 0, stream>>>(rp, esrc, dis, ew, N);
  for (int l = 0; l < 2; ++l) {
    k_wt<<<(HDIM * HDIM + 255) / 256, 256, 0, stream>>>(gw[l], gwT[l], HDIM, HDIM, HDIM);
    k_wt4<<<(512 * 384 + 255) / 256, 256, 0, stream>>>(wg[l][0], wg[l][1], wg[l][2], wg[l][3], w4T[l]);
    k_bias4<<<2, 256, 0, stream>>>(bg[l][0], bg[l][1], bg[l][2], bg[l][3], b4[l]);
  }

  // batched layer-0 GCN: all 12 timesteps at once
  k_gemm<<<dim3((tnh / HDIM + 127) / 128, 1), 256, 0, stream>>>(xb, gwT[0], xw_all, tnh / HDIM);
  k_agg<<<TSTEPS * N, 64, 0, stream>>>(xw_all, rp, esrc, ew, selfn, gb[0], g0_all, N);

  // recurrent loop
  u16 *h0r = h0A, *h0w = h0B, *h1r = h1A, *h1w = h1B;
  dim3 gGate((N + 127) / 128, 4), gGcn((N + 127) / 128, 1);
  for (int t = 0; t < TSTEPS; ++t) {
    const u16* xt = xb + (size_t)t * nh;
    k_gemm_gate<<<gGate, 256, 0, stream>>>(xt, g0_all + (size_t)t * nh, h0r, w4T[0], b4[0], cst[0], h0w, N);
    k_gemm<<<gGcn, 256, 0, stream>>>(h0w, gwT[1], xw1, N);
    k_agg<<<N, 64, 0, stream>>>(xw1, rp, esrc, ew, selfn, gb[1], g1buf, N);
    k_gemm_gate<<<gGate, 256, 0, stream>>>(h0w, g1buf, h1r, w4T[1], b4[1], cst[1], h1w, N);
    u16* tmp = h0r; h0r = h0w; h0w = tmp;
    tmp = h1r; h1r = h1w; h1w = tmp;
  }
  k_out<<<(N + 3) / 4, 256, 0, stream>>>(h1r, ow, ob, out, N);
}

// Round 3
// 1565.889 us; speedup vs baseline: 1.4061x; 1.1537x over previous
//
#include <hip/hip_runtime.h>
#include <hip/hip_bf16.h>

typedef unsigned short u16;
typedef unsigned int   u32;
typedef __attribute__((ext_vector_type(8))) short bf16x8;
typedef __attribute__((ext_vector_type(4))) float f32x4;

#define HDIM 128
#define TSTEPS 12
#define OUTD 64

#define AS1 __attribute__((address_space(1)))
#define AS3 __attribute__((address_space(3)))

__device__ __forceinline__ void glds16(const void* g, void* l) {
  __builtin_amdgcn_global_load_lds((const AS1 u32*)g, (AS3 u32*)l, 16, 0, 0);
}

__device__ __forceinline__ float bfu(u32 lo16) {
  union { u32 u; float f; } v; v.u = lo16 << 16; return v.f;
}
__device__ __forceinline__ u16 f2bf(float x) {
  union { float f; u32 u; } v; v.f = x;
  return (u16)((v.u + 0x7fffu + ((v.u >> 16) & 1u)) >> 16);
}
__device__ __forceinline__ float sigm(float x) { return 1.0f / (1.0f + __expf(-x)); }
__device__ __forceinline__ float tanh_f(float x) { return 1.0f - 2.0f / (__expf(2.0f * x) + 1.0f); }

// ---------------- setup kernels ----------------

__global__ void k_init(float* c0, float* c1, u16* h0a, u16* h0b, u16* h1a, u16* h1b,
                       int* cnt, int* cursor, int N) {
  int i = blockIdx.x * 256 + threadIdx.x;
  int nh = N * HDIM;
  if (i < nh) { c0[i] = 0.f; c1[i] = 0.f; h0a[i] = 0; h0b[i] = 0; h1a[i] = 0; h1b[i] = 0; }
  if (i < N) { cnt[i] = 0; cursor[i] = 0; }
}

// x (N,128,12) f32 -> xb (12,N,128) bf16
__global__ void k_xpose(const float* __restrict__ x, u16* __restrict__ xb, int N) {
  int i = blockIdx.x * 256 + threadIdx.x;  // (n,f)
  if (i >= N * HDIM) return;
  const float* src = x + (size_t)i * 12;
  float4 a = *(const float4*)src;
  float4 b = *(const float4*)(src + 4);
  float4 c = *(const float4*)(src + 8);
  float v[12] = { a.x,a.y,a.z,a.w,b.x,b.y,b.z,b.w,c.x,c.y,c.z,c.w };
#pragma unroll
  for (int t = 0; t < 12; ++t) xb[(size_t)t * N * HDIM + i] = f2bf(v[t]);
}

__global__ void k_cnt(const int* __restrict__ ei, int* cnt, int E) {
  int e = blockIdx.x * 256 + threadIdx.x;
  if (e >= E) return;
  atomicAdd(&cnt[ei[E + e]], 1);
}

__global__ void k_scan(const int* __restrict__ cnt, int* __restrict__ rp, int n) {
  __shared__ int sums[1024];
  int tid = threadIdx.x;
  int chunk = (n + 1023) / 1024;
  int start = tid * chunk;
  int end = start + chunk; if (end > n) end = n;
  int s = 0;
  for (int i = start; i < end; ++i) s += cnt[i];
  sums[tid] = s;
  __syncthreads();
  for (int off = 1; off < 1024; off <<= 1) {
    int v = (tid >= off) ? sums[tid - off] : 0;
    __syncthreads();
    sums[tid] += v;
    __syncthreads();
  }
  int run = (tid == 0) ? 0 : sums[tid - 1];
  for (int i = start; i < end; ++i) { rp[i] = run; run += cnt[i]; }
  if (tid == 1023) rp[n] = sums[1023];
}

__global__ void k_scatter(const int* __restrict__ ei, const float* __restrict__ ea,
                          const int* __restrict__ rp, int* cursor,
                          int* esrc, float* ew, int E) {
  int e = blockIdx.x * 256 + threadIdx.x;
  if (e >= E) return;
  int row = ei[e], col = ei[E + e];
  int pos = atomicAdd(&cursor[col], 1);
  int idx = rp[col] + pos;
  esrc[idx] = row;
  ew[idx] = ea[e * 4 + 3];
}

__global__ void k_degcsr(const int* __restrict__ rp, const float* __restrict__ ew,
                         float* dis, float* selfn, int N) {
  int j = blockIdx.x;
  int lane = threadIdx.x;  // 64
  int beg = rp[j], end = rp[j + 1];
  float s = 0.f;
  for (int i = beg + lane; i < end; i += 64) s += ew[i];
#pragma unroll
  for (int o = 32; o; o >>= 1) s += __shfl_down(s, o);
  if (lane == 0) {
    float d = 1.0f + s;
    dis[j] = rsqrtf(d);
    selfn[j] = 1.0f / d;
  }
}

__global__ void k_enrm(const int* __restrict__ rp, const int* __restrict__ esrc,
                       const float* __restrict__ dis, float* ew, int N) {
  int j = blockIdx.x;
  int lane = threadIdx.x;  // 64
  int beg = rp[j], end = rp[j + 1];
  float dj = dis[j];
  for (int i = beg + lane; i < end; i += 64) ew[i] = dis[esrc[i]] * ew[i] * dj;
}

__global__ void k_wt(const float* __restrict__ src, u16* __restrict__ dst, int K, int J, int ldK) {
  int idx = blockIdx.x * 256 + threadIdx.x;
  if (idx >= K * J) return;
  int k = idx / J, j = idx % J;
  dst[j * ldK + k] = f2bf(src[idx]);
}

// fused gate weights, column-permuted: p[3:0]=hc_lo, p[5:4]=gate, p[8:6]=hc_hi
__global__ void k_wt4(const float* wf, const float* wi, const float* wo, const float* wc,
                      u16* __restrict__ dst) {
  int idx = blockIdx.x * 256 + threadIdx.x;  // 512*384
  if (idx >= 512 * 384) return;
  int p = idx / 384, k = idx % 384;
  int g = (p >> 4) & 3;
  int hc = (p & 15) | ((p >> 6) << 4);
  const float* w[4] = { wf, wi, wo, wc };
  dst[p * 384 + k] = f2bf(w[g][k * HDIM + hc]);
}

__global__ void k_bias4(const float* bf, const float* bi, const float* bo, const float* bc,
                        float* dst) {
  int p = blockIdx.x * 256 + threadIdx.x;
  if (p >= 512) return;
  int g = (p >> 4) & 3;
  int hc = (p & 15) | ((p >> 6) << 4);
  const float* b[4] = { bf, bi, bo, bc };
  dst[p] = b[g][hc];
}

// ---------------- MFMA GEMM (NT), global_load_lds staging ----------------
// C[M,128] = A[M,128] * wt[128,128]^T -> bf16
__global__ __launch_bounds__(256)
void k_gemm(const u16* __restrict__ A, const u16* __restrict__ wt,
            u16* __restrict__ Cb, int M) {
  __shared__ u16 lA[128 * 32];
  __shared__ u16 lB[128 * 32];
  const int tid = threadIdx.x;
  const int row0 = blockIdx.x * 128;
  const int wave = tid >> 6, lane = tid & 63;
  const int wm = (wave >> 1) * 64, wn = (wave & 1) * 64;
  const int fr = lane & 15, fk = (lane >> 4) * 8;
  const int lr = tid >> 2, lc = (tid & 3) * 8;

  u16* ldA = lA + wave * 512;   // wave-uniform base (bytes: wave*1024)
  u16* ldB = lB + wave * 512;
  const u16* ga1 = A + (size_t)(row0 + lr) * HDIM + lc;
  const u16* ga2 = ga1 + (size_t)64 * HDIM;
  const u16* gb1 = wt + (size_t)lr * HDIM + lc;
  const u16* gb2 = gb1 + (size_t)64 * HDIM;

  f32x4 acc[4][4] = {};

  for (int k0 = 0; k0 < 128; k0 += 32) {
    glds16(ga1 + k0, ldA);
    glds16(ga2 + k0, ldA + 2048);
    glds16(gb1 + k0, ldB);
    glds16(gb2 + k0, ldB + 2048);
    __syncthreads();
    bf16x8 af[4], bfx[4];
#pragma unroll
    for (int m = 0; m < 4; ++m) af[m]  = *(const bf16x8*)&lA[(wm + m * 16 + fr) * 32 + fk];
#pragma unroll
    for (int n = 0; n < 4; ++n) bfx[n] = *(const bf16x8*)&lB[(wn + n * 16 + fr) * 32 + fk];
#pragma unroll
    for (int m = 0; m < 4; ++m)
#pragma unroll
      for (int n = 0; n < 4; ++n)
        acc[m][n] = __builtin_amdgcn_mfma_f32_16x16x32_bf16(af[m], bfx[n], acc[m][n], 0, 0, 0);
    __syncthreads();
  }

  const int fq4 = (lane >> 4) * 4;
#pragma unroll
  for (int m = 0; m < 4; ++m)
#pragma unroll
    for (int n = 0; n < 4; ++n) {
      const int colg = wn + n * 16 + fr;
#pragma unroll
      for (int i = 0; i < 4; ++i) {
        const int rowg = row0 + wm + m * 16 + fq4 + i;
        if (rowg < M) Cb[(size_t)rowg * HDIM + colg] = f2bf(acc[m][n][i]);
      }
    }
}

// ------------- fused gates GEMM + LSTM cell epilogue (dual, grid.z selects) -------------
struct GA {
  const u16* s0; const u16* s1; const u16* s2;   // K segments (each M x 128)
  const u16* wt;                                 // 512 x 384 col-permuted
  const float* b4; float* cst; u16* hout;
};

__global__ __launch_bounds__(256)
void k_gate(GA ga0, GA ga1, int M) {
  __shared__ u16 lA[128 * 32];
  __shared__ u16 lB[128 * 32];
  const GA& ga = (blockIdx.z == 0) ? ga0 : ga1;
  const u16* segs[3] = { ga.s0, ga.s1, ga.s2 };
  const int tid = threadIdx.x;
  const int row0 = blockIdx.x * 128;
  const int col0 = blockIdx.y * 128;
  const int wave = tid >> 6, lane = tid & 63;
  const int wm = (wave >> 1) * 64, wn = (wave & 1) * 64;
  const int fr = lane & 15, fk = (lane >> 4) * 8;
  const int lr = tid >> 2, lc = (tid & 3) * 8;

  u16* ldA = lA + wave * 512;
  u16* ldB = lB + wave * 512;
  const u16* gb1 = ga.wt + (size_t)(col0 + lr) * 384 + lc;
  const u16* gb2 = gb1 + (size_t)64 * 384;
  const size_t arow1 = (size_t)(row0 + lr) * HDIM + lc;
  const size_t arow2 = arow1 + (size_t)64 * HDIM;

  f32x4 acc[4][4] = {};

  for (int ks = 0; ks < 12; ++ks) {
    const int k0 = ks * 32;
    const u16* As = segs[ks >> 2];
    const int kk = k0 & 127;
    glds16(As + arow1 + kk, ldA);
    glds16(As + arow2 + kk, ldA + 2048);
    glds16(gb1 + k0, ldB);
    glds16(gb2 + k0, ldB + 2048);
    __syncthreads();
    bf16x8 af[4], bfx[4];
#pragma unroll
    for (int m = 0; m < 4; ++m) af[m]  = *(const bf16x8*)&lA[(wm + m * 16 + fr) * 32 + fk];
#pragma unroll
    for (int n = 0; n < 4; ++n) bfx[n] = *(const bf16x8*)&lB[(wn + n * 16 + fr) * 32 + fk];
#pragma unroll
    for (int m = 0; m < 4; ++m)
#pragma unroll
      for (int n = 0; n < 4; ++n)
        acc[m][n] = __builtin_amdgcn_mfma_f32_16x16x32_bf16(af[m], bfx[n], acc[m][n], 0, 0, 0);
    __syncthreads();
  }

  // epilogue: lane's 4 n-fragments are gates f,i,o,c of channel hc
  const int fq4 = (lane >> 4) * 4;
  const int hc = fr | ((blockIdx.y * 2 + (wave & 1)) << 4);
  const int colbase = col0 + wn + fr;
  const float bb0 = ga.b4[colbase];
  const float bb1 = ga.b4[colbase + 16];
  const float bb2 = ga.b4[colbase + 32];
  const float bb3 = ga.b4[colbase + 48];
#pragma unroll
  for (int m = 0; m < 4; ++m)
#pragma unroll
    for (int i = 0; i < 4; ++i) {
      const int rowg = row0 + wm + m * 16 + fq4 + i;
      if (rowg < M) {
        float f_ = sigm(acc[m][0][i] + bb0);
        float i_ = sigm(acc[m][1][i] + bb1);
        float o_ = sigm(acc[m][2][i] + bb2);
        float cd = tanh_f(acc[m][3][i] + bb3);
        size_t idx = (size_t)rowg * HDIM + hc;
        float cn = f_ * ga.cst[idx] + i_ * cd;
        ga.cst[idx] = cn;
        ga.hout[idx] = f2bf(o_ * tanh_f(cn));
      }
    }
}

// ---------------- CSR gather aggregation + sigmoid -> g (bf16) ----------------
// batched: blockIdx.x in [0, B*N); node = bid % N; rows offset by (bid - node)
__global__ void k_agg(const u16* __restrict__ xw, const int* __restrict__ rp,
                      const int* __restrict__ esrc, const float* __restrict__ enrm,
                      const float* __restrict__ selfn, const float* __restrict__ gb,
                      u16* __restrict__ g, int N) {
  __shared__ u32   s_off[64];
  __shared__ float s_nrm[64];
  const char* xwb = (const char*)xw;
  int bid = blockIdx.x;
  int j = bid % N;
  u32 tbase = (u32)(bid - j) << 8;   // byte offset of t-slab start
  int lane = threadIdx.x;            // 64
  int beg = rp[j], end = rp[j + 1];
  float sn = selfn[j];
  const u32 laneB = (u32)lane * 4;
  u32 v = *(const u32*)(xwb + (((u32)bid << 8) + laneB));
  float a0 = sn * bfu(v & 0xffffu);
  float a1 = sn * bfu(v >> 16);
  float c0 = 0.f, c1 = 0.f;
  for (int cb = beg; cb < end; cb += 64) {
    int m = end - cb; if (m > 64) m = 64;
    if (lane < m) {
      s_off[lane] = tbase + ((u32)esrc[cb + lane] << 8);
      s_nrm[lane] = enrm[cb + lane];
    }
    __syncthreads();
    int e = 0;
    for (; e + 1 < m; e += 2) {
      u32 o0 = s_off[e], o1 = s_off[e + 1];
      float w0 = s_nrm[e], w1 = s_nrm[e + 1];
      u32 v0 = *(const u32*)(xwb + (o0 + laneB));
      u32 v1 = *(const u32*)(xwb + (o1 + laneB));
      a0 += w0 * bfu(v0 & 0xffffu);
      a1 += w0 * bfu(v0 >> 16);
      c0 += w1 * bfu(v1 & 0xffffu);
      c1 += w1 * bfu(v1 >> 16);
    }
    if (e < m) {
      u32 o0 = s_off[e];
      float w0 = s_nrm[e];
      u32 v0 = *(const u32*)(xwb + (o0 + laneB));
      a0 += w0 * bfu(v0 & 0xffffu);
      a1 += w0 * bfu(v0 >> 16);
    }
    __syncthreads();
  }
  a0 = sigm(a0 + c0 + gb[lane * 2]);
  a1 = sigm(a1 + c1 + gb[lane * 2 + 1]);
  u32 outp = ((u32)f2bf(a1) << 16) | (u32)f2bf(a0);
  *(u32*)(g + (size_t)bid * HDIM + lane * 2) = outp;
}

// ---------------- output projection: out = h1 @ ow + ob ----------------
__global__ void k_out(const u16* __restrict__ h, const float* __restrict__ ow,
                      const float* __restrict__ ob, float* __restrict__ out, int M) {
  __shared__ float lw[HDIM * OUTD];
  __shared__ float lb[OUTD];
  int tid = threadIdx.x;  // 256
  for (int i = tid; i < HDIM * OUTD; i += 256) lw[i] = ow[i];
  if (tid < OUTD) lb[tid] = ob[tid];
  __syncthreads();
  int j = tid & 63;
  int nl = tid >> 6;
  int n = blockIdx.x * 4 + nl;
  if (n >= M) return;
  const u16* hr = h + (size_t)n * HDIM;
  float s = lb[j];
#pragma unroll 4
  for (int k = 0; k < HDIM; ++k) s += bfu(hr[k]) * lw[k * OUTD + j];
  out[(size_t)n * OUTD + j] = s;
}

// ---------------- host ----------------
extern "C" void kernel_launch(void* const* d_in, const int* in_sizes, int n_in,
                              void* d_out, int out_size, void* d_ws, size_t ws_size,
                              hipStream_t stream) {
  const float* x  = (const float*)d_in[0];
  const float* ea = (const float*)d_in[1];
  const int*   ei = (const int*)d_in[2];
  const float* gw[2] = { (const float*)d_in[3],  (const float*)d_in[13] };
  const float* gb[2] = { (const float*)d_in[4],  (const float*)d_in[14] };
  const float* wg[2][4] = {
    { (const float*)d_in[5],  (const float*)d_in[7],  (const float*)d_in[9],  (const float*)d_in[11] },
    { (const float*)d_in[15], (const float*)d_in[17], (const float*)d_in[19], (const float*)d_in[21] } };
  const float* bg[2][4] = {
    { (const float*)d_in[6],  (const float*)d_in[8],  (const float*)d_in[10], (const float*)d_in[12] },
    { (const float*)d_in[16], (const float*)d_in[18], (const float*)d_in[20], (const float*)d_in[22] } };
  const float* ow = (const float*)d_in[23];
  const float* ob = (const float*)d_in[24];
  float* out = (float*)d_out;

  const int N = in_sizes[0] / (HDIM * TSTEPS);
  const int E = in_sizes[2] / 2;
  const int nh = N * HDIM;
  const int tnh = TSTEPS * nh;

  size_t off = 0;
  auto alloc = [&](size_t bytes) -> void* {
    void* p = (char*)d_ws + off;
    off += (bytes + 255) & ~(size_t)255;
    return p;
  };
  u16* xb     = (u16*)alloc((size_t)tnh * 2);
  u16* xw_all = (u16*)alloc((size_t)tnh * 2);
  u16* g0_all = (u16*)alloc((size_t)tnh * 2);
  u16* h0A = (u16*)alloc((size_t)nh * 2);
  u16* h0B = (u16*)alloc((size_t)nh * 2);
  u16* h1A = (u16*)alloc((size_t)nh * 2);
  u16* h1B = (u16*)alloc((size_t)nh * 2);
  u16* g1buf = (u16*)alloc((size_t)nh * 2);
  u16* xw1   = (u16*)alloc((size_t)nh * 2);
  float* cst[2] = { (float*)alloc((size_t)nh * 4), (float*)alloc((size_t)nh * 4) };
  float* dis   = (float*)alloc((size_t)N * 4);
  float* selfn = (float*)alloc((size_t)N * 4);
  int* cnt     = (int*)alloc((size_t)N * 4);
  int* cursor  = (int*)alloc((size_t)N * 4);
  int* rp      = (int*)alloc((size_t)(N + 1) * 4);
  int* esrc    = (int*)alloc((size_t)E * 4);
  float* ew    = (float*)alloc((size_t)E * 4);
  u16* gwT[2] = { (u16*)alloc(HDIM * HDIM * 2), (u16*)alloc(HDIM * HDIM * 2) };
  u16* w4T[2] = { (u16*)alloc(512 * 384 * 2),   (u16*)alloc(512 * 384 * 2) };
  float* b4[2] = { (float*)alloc(512 * 4), (float*)alloc(512 * 4) };
  alloc(32768);  // slack so OOB tile reads (<=96 rows) stay mapped

  // setup
  k_init<<<(nh + 255) / 256, 256, 0, stream>>>(cst[0], cst[1], h0A, h0B, h1A, h1B, cnt, cursor, N);
  k_xpose<<<(nh + 255) / 256, 256, 0, stream>>>(x, xb, N);
  k_cnt<<<(E + 255) / 256, 256, 0, stream>>>(ei, cnt, E);
  k_scan<<<1, 1024, 0, stream>>>(cnt, rp, N);
  k_scatter<<<(E + 255) / 256, 256, 0, stream>>>(ei, ea, rp, cursor, esrc, ew, E);
  k_degcsr<<<N, 64, 0, stream>>>(rp, ew, dis, selfn, N);
  k_enrm<<<N, 64, 0, stream>>>(rp, esrc, dis, ew, N);
  for (int l = 0; l < 2; ++l) {
    k_wt<<<(HDIM * HDIM + 255) / 256, 256, 0, stream>>>(gw[l], gwT[l], HDIM, HDIM, HDIM);
    k_wt4<<<(512 * 384 + 255) / 256, 256, 0, stream>>>(wg[l][0], wg[l][1], wg[l][2], wg[l][3], w4T[l]);
    k_bias4<<<2, 256, 0, stream>>>(bg[l][0], bg[l][1], bg[l][2], bg[l][3], b4[l]);
  }

  // batched layer-0 GCN: all 12 timesteps at once
  k_gemm<<<dim3(tnh / HDIM / 128, 1), 256, 0, stream>>>(xb, gwT[0], xw_all, tnh / HDIM);
  k_agg<<<TSTEPS * N, 64, 0, stream>>>(xw_all, rp, esrc, ew, selfn, gb[0], g0_all, N);

  // recurrent loop
  u16 *h0cur = h0A, *h0alt = h0B, *h1cur = h1A, *h1alt = h1B;
  const int nb = (N + 127) / 128;

  // prologue: gate0 for t=0 (h0_{-1} = zeros in h0cur)
  {
    GA a0 = { xb, g0_all, h0cur, w4T[0], b4[0], cst[0], h0alt };
    k_gate<<<dim3(nb, 4, 1), 256, 0, stream>>>(a0, a0, N);
    u16* tmp = h0cur; h0cur = h0alt; h0alt = tmp;
  }

  for (int t = 0; t < TSTEPS; ++t) {
    k_gemm<<<dim3(nb, 1), 256, 0, stream>>>(h0cur, gwT[1], xw1, N);
    k_agg<<<N, 64, 0, stream>>>(xw1, rp, esrc, ew, selfn, gb[1], g1buf, N);
    GA a0 = { h0cur, g1buf, h1cur, w4T[1], b4[1], cst[1], h1alt };  // gate1_t
    if (t + 1 < TSTEPS) {
      GA a1 = { xb + (size_t)(t + 1) * nh, g0_all + (size_t)(t + 1) * nh, h0cur,
                w4T[0], b4[0], cst[0], h0alt };                      // gate0_{t+1}
      k_gate<<<dim3(nb, 4, 2), 256, 0, stream>>>(a0, a1, N);
      u16* tmp = h0cur; h0cur = h0alt; h0alt = tmp;
    } else {
      k_gate<<<dim3(nb, 4, 1), 256, 0, stream>>>(a0, a0, N);
    }
    u16* tmp = h1cur; h1cur = h1alt; h1alt = tmp;
  }
  k_out<<<(N + 3) / 4, 256, 0, stream>>>(h1cur, ow, ob, out, N);
}

// Round 4
// 1438.966 us; speedup vs baseline: 1.5301x; 1.0882x over previous
//
#include <hip/hip_runtime.h>
#include <hip/hip_bf16.h>

typedef unsigned short u16;
typedef unsigned int   u32;
typedef __attribute__((ext_vector_type(8))) short bf16x8;
typedef __attribute__((ext_vector_type(4))) float f32x4;

#define HDIM 128
#define TSTEPS 12
#define OUTD 64

#define AS1 __attribute__((address_space(1)))
#define AS3 __attribute__((address_space(3)))

__device__ __forceinline__ void glds16(const void* g, void* l) {
  __builtin_amdgcn_global_load_lds((const AS1 u32*)g, (AS3 u32*)l, 16, 0, 0);
}

__device__ __forceinline__ float bflo(u32 u) { return __uint_as_float(u << 16); }
__device__ __forceinline__ float bfhi(u32 u) { return __uint_as_float(u & 0xffff0000u); }
__device__ __forceinline__ u16 f2bf(float x) {
  union { float f; u32 u; } v; v.f = x;
  return (u16)((v.u + 0x7fffu + ((v.u >> 16) & 1u)) >> 16);
}
__device__ __forceinline__ float sigm(float x) { return 1.0f / (1.0f + __expf(-x)); }
__device__ __forceinline__ float tanh_f(float x) { return 1.0f - 2.0f / (__expf(2.0f * x) + 1.0f); }

// ---------------- setup kernels ----------------

__global__ void k_init(float* c0, float* c1, u16* h0z, u16* h1z, int* cnt, int* cursor, int N) {
  int i = blockIdx.x * 256 + threadIdx.x;
  int nh = N * HDIM;
  if (i < nh) { c0[i] = 0.f; c1[i] = 0.f; h0z[i] = 0; h1z[i] = 0; }
  if (i < N) { cnt[i] = 1; cursor[i] = 0; }   // cnt=1 reserves the self-loop slot
}

// x (N,128,12) f32 -> xb (12,N,128) bf16
__global__ void k_xpose(const float* __restrict__ x, u16* __restrict__ xb, int N) {
  int i = blockIdx.x * 256 + threadIdx.x;  // (n,f)
  if (i >= N * HDIM) return;
  const float* src = x + (size_t)i * 12;
  float4 a = *(const float4*)src;
  float4 b = *(const float4*)(src + 4);
  float4 c = *(const float4*)(src + 8);
  float v[12] = { a.x,a.y,a.z,a.w,b.x,b.y,b.z,b.w,c.x,c.y,c.z,c.w };
#pragma unroll
  for (int t = 0; t < 12; ++t) xb[(size_t)t * N * HDIM + i] = f2bf(v[t]);
}

__global__ void k_cnt(const int* __restrict__ ei, int* cnt, int E) {
  int e = blockIdx.x * 256 + threadIdx.x;
  if (e >= E) return;
  atomicAdd(&cnt[ei[E + e]], 1);
}

__global__ void k_scan(const int* __restrict__ cnt, int* __restrict__ rp, int n) {
  __shared__ int sums[1024];
  int tid = threadIdx.x;
  int chunk = (n + 1023) / 1024;
  int start = tid * chunk;
  int end = start + chunk; if (end > n) end = n;
  int s = 0;
  for (int i = start; i < end; ++i) s += cnt[i];
  sums[tid] = s;
  __syncthreads();
  for (int off = 1; off < 1024; off <<= 1) {
    int v = (tid >= off) ? sums[tid - off] : 0;
    __syncthreads();
    sums[tid] += v;
    __syncthreads();
  }
  int run = (tid == 0) ? 0 : sums[tid - 1];
  for (int i = start; i < end; ++i) { rp[i] = run; run += cnt[i]; }
  if (tid == 1023) rp[n] = sums[1023];
}

// edges -> interleaved {src_row_byteoff, raw_w}; slot rp[col]+0 reserved for self
__global__ void k_scatter(const int* __restrict__ ei, const float* __restrict__ ea,
                          const int* __restrict__ rp, int* cursor, uint2* ee, int E) {
  int e = blockIdx.x * 256 + threadIdx.x;
  if (e >= E) return;
  int row = ei[e], col = ei[E + e];
  int pos = atomicAdd(&cursor[col], 1);
  int idx = rp[col] + 1 + pos;
  ee[idx] = make_uint2((u32)row << 8, __float_as_uint(ea[e * 4 + 3]));
}

// per-node raw-weight sum (excl. self slot) -> dis; writes the self slot
__global__ void k_degcsr(const int* __restrict__ rp, uint2* ee, float* dis, int N) {
  int j = blockIdx.x;
  int lane = threadIdx.x;  // 64
  int beg = rp[j], end = rp[j + 1];
  float s = 0.f;
  for (int i = beg + 1 + lane; i < end; i += 64) s += __uint_as_float(ee[i].y);
#pragma unroll
  for (int o = 32; o; o >>= 1) s += __shfl_down(s, o);
  if (lane == 0) {
    dis[j] = rsqrtf(1.0f + s);
    ee[beg] = make_uint2((u32)j << 8, __float_as_uint(1.0f));  // self-loop raw w = 1
  }
}

__global__ void k_enrm(const int* __restrict__ rp, const float* __restrict__ dis,
                       uint2* ee, int N) {
  int j = blockIdx.x;
  int lane = threadIdx.x;  // 64
  int beg = rp[j], end = rp[j + 1];
  float dj = dis[j];
  for (int i = beg + lane; i < end; i += 64) {
    uint2 q = ee[i];
    ee[i].y = __float_as_uint(dis[q.x >> 8] * __uint_as_float(q.y) * dj);
  }
}

__global__ void k_wt(const float* __restrict__ src, u16* __restrict__ dst, int K, int J, int ldK) {
  int idx = blockIdx.x * 256 + threadIdx.x;
  if (idx >= K * J) return;
  int k = idx / J, j = idx % J;
  dst[j * ldK + k] = f2bf(src[idx]);
}

// fused gate weights, column-permuted: p[3:0]=hc_lo, p[5:4]=gate, p[8:6]=hc_hi
__global__ void k_wt4(const float* wf, const float* wi, const float* wo, const float* wc,
                      u16* __restrict__ dst) {
  int idx = blockIdx.x * 256 + threadIdx.x;  // 512*384
  if (idx >= 512 * 384) return;
  int p = idx / 384, k = idx % 384;
  int g = (p >> 4) & 3;
  int hc = (p & 15) | ((p >> 6) << 4);
  const float* w[4] = { wf, wi, wo, wc };
  dst[p * 384 + k] = f2bf(w[g][k * HDIM + hc]);
}

__global__ void k_bias4(const float* bf, const float* bi, const float* bo, const float* bc,
                        float* dst) {
  int p = blockIdx.x * 256 + threadIdx.x;
  if (p >= 512) return;
  int g = (p >> 4) & 3;
  int hc = (p & 15) | ((p >> 6) << 4);
  const float* b[4] = { bf, bi, bo, bc };
  dst[p] = b[g][hc];
}

// ---------------- mega kernel: gate jobs (y in [0,4*ngate)) + optional plain GEMM (y == 4*ngate) ----
struct GA {
  const u16* s0; const u16* s1; const u16* s2;   // K segments (each M x 128)
  const u16* wt;                                 // 512 x 384 col-permuted
  const float* b4; float* cst; u16* hout;
};
struct GJ { const u16* A; const u16* wt; u16* out; };

__global__ __launch_bounds__(256)
void k_mega(GA ga0, GA ga1, GJ gj, int gjM, int ngate, int M) {
  __shared__ u16 lA[128 * 32];
  __shared__ u16 lB[128 * 32];
  const int y = blockIdx.y;
  const int tid = threadIdx.x;
  const int row0 = blockIdx.x * 128;
  const int wave = tid >> 6, lane = tid & 63;
  const int wm = (wave >> 1) * 64, wn = (wave & 1) * 64;
  const int fr = lane & 15, fk = (lane >> 4) * 8;
  const int lr = tid >> 2, lc = (tid & 3) * 8;
  u16* ldA = lA + wave * 512;
  u16* ldB = lB + wave * 512;
  f32x4 acc[4][4] = {};
  const int fq4 = (lane >> 4) * 4;

  if (y < 4 * ngate) {
    // ---- gate job ----
    const GA& ga = (y < 4) ? ga0 : ga1;
    const int yy = y & 3;
    const int col0 = yy * 128;
    const u16* segs[3] = { ga.s0, ga.s1, ga.s2 };
    const u16* gb1 = ga.wt + (size_t)(col0 + lr) * 384 + lc;
    const u16* gb2 = gb1 + (size_t)64 * 384;
    const size_t arow1 = (size_t)(row0 + lr) * HDIM + lc;
    const size_t arow2 = arow1 + (size_t)64 * HDIM;

    for (int ks = 0; ks < 12; ++ks) {
      const int k0 = ks * 32;
      const u16* As = segs[ks >> 2];
      const int kk = k0 & 127;
      glds16(As + arow1 + kk, ldA);
      glds16(As + arow2 + kk, ldA + 2048);
      glds16(gb1 + k0, ldB);
      glds16(gb2 + k0, ldB + 2048);
      __syncthreads();
      bf16x8 af[4], bfx[4];
#pragma unroll
      for (int m = 0; m < 4; ++m) af[m]  = *(const bf16x8*)&lA[(wm + m * 16 + fr) * 32 + fk];
#pragma unroll
      for (int n = 0; n < 4; ++n) bfx[n] = *(const bf16x8*)&lB[(wn + n * 16 + fr) * 32 + fk];
#pragma unroll
      for (int m = 0; m < 4; ++m)
#pragma unroll
        for (int n = 0; n < 4; ++n)
          acc[m][n] = __builtin_amdgcn_mfma_f32_16x16x32_bf16(af[m], bfx[n], acc[m][n], 0, 0, 0);
      __syncthreads();
    }

    const int hc = fr | ((yy * 2 + (wave & 1)) << 4);
    const int colbase = col0 + wn + fr;
    const float bb0 = ga.b4[colbase];
    const float bb1 = ga.b4[colbase + 16];
    const float bb2 = ga.b4[colbase + 32];
    const float bb3 = ga.b4[colbase + 48];
#pragma unroll
    for (int m = 0; m < 4; ++m)
#pragma unroll
      for (int i = 0; i < 4; ++i) {
        const int rowg = row0 + wm + m * 16 + fq4 + i;
        if (rowg < M) {
          float f_ = sigm(acc[m][0][i] + bb0);
          float i_ = sigm(acc[m][1][i] + bb1);
          float o_ = sigm(acc[m][2][i] + bb2);
          float cd = tanh_f(acc[m][3][i] + bb3);
          size_t idx = (size_t)rowg * HDIM + hc;
          float cn = f_ * ga.cst[idx] + i_ * cd;
          ga.cst[idx] = cn;
          ga.hout[idx] = f2bf(o_ * tanh_f(cn));
        }
      }
  } else {
    // ---- plain 128x128 GEMM job: out = A @ wt^T (bf16) ----
    if (row0 >= gjM) return;
    const u16* ga1p = gj.A + (size_t)(row0 + lr) * HDIM + lc;
    const u16* ga2p = ga1p + (size_t)64 * HDIM;
    const u16* gb1p = gj.wt + (size_t)lr * HDIM + lc;
    const u16* gb2p = gb1p + (size_t)64 * HDIM;
    for (int k0 = 0; k0 < 128; k0 += 32) {
      glds16(ga1p + k0, ldA);
      glds16(ga2p + k0, ldA + 2048);
      glds16(gb1p + k0, ldB);
      glds16(gb2p + k0, ldB + 2048);
      __syncthreads();
      bf16x8 af[4], bfx[4];
#pragma unroll
      for (int m = 0; m < 4; ++m) af[m]  = *(const bf16x8*)&lA[(wm + m * 16 + fr) * 32 + fk];
#pragma unroll
      for (int n = 0; n < 4; ++n) bfx[n] = *(const bf16x8*)&lB[(wn + n * 16 + fr) * 32 + fk];
#pragma unroll
      for (int m = 0; m < 4; ++m)
#pragma unroll
        for (int n = 0; n < 4; ++n)
          acc[m][n] = __builtin_amdgcn_mfma_f32_16x16x32_bf16(af[m], bfx[n], acc[m][n], 0, 0, 0);
      __syncthreads();
    }
#pragma unroll
    for (int m = 0; m < 4; ++m)
#pragma unroll
      for (int n = 0; n < 4; ++n) {
        const int colg = wn + n * 16 + fr;
#pragma unroll
        for (int i = 0; i < 4; ++i) {
          const int rowg = row0 + wm + m * 16 + fq4 + i;
          if (rowg < gjM) gj.out[(size_t)rowg * HDIM + colg] = f2bf(acc[m][n][i]);
        }
      }
  }
}

// ---------------- CSR gather aggregation + sigmoid -> g (bf16) ----------------
// half-wave per edge, 8B/lane; self-loop is CSR slot 0. blockIdx.x=(t,node), node=bid%N.
__global__ void k_agg(const u16* __restrict__ xw, const int* __restrict__ rp,
                      const uint2* __restrict__ ee, const float* __restrict__ gb,
                      u16* __restrict__ g, int N) {
  __shared__ uint2 s_e[64];
  const char* xwb = (const char*)xw;
  int bid = blockIdx.x;
  int j = bid % N;
  u32 tbase = (u32)(bid - j) << 8;   // byte offset of this t-slab
  int lane = threadIdx.x;            // 64
  int beg = rp[j], end = rp[j + 1];
  const int sl = lane & 31, half = lane >> 5;
  const u32 slB = (u32)sl * 8;
  float a0 = 0.f, a1 = 0.f, a2 = 0.f, a3 = 0.f;
  for (int cb = beg; cb < end; cb += 64) {
    int mc = end - cb; if (mc > 64) mc = 64;
    uint2 q;
    if (lane < mc) { q = ee[cb + lane]; q.x += tbase; }
    else { q.x = tbase; q.y = 0u; }   // pad: valid addr, zero weight
    s_e[lane] = q;
    __syncthreads();
    int np = (mc + 1) >> 1;
    for (int p = 0; p < np; ++p) {
      uint2 r = s_e[p * 2 + half];
      float w = __uint_as_float(r.y);
      uint2 v = *(const uint2*)(xwb + (r.x + slB));
      a0 += w * bflo(v.x);
      a1 += w * bfhi(v.x);
      a2 += w * bflo(v.y);
      a3 += w * bfhi(v.y);
    }
    __syncthreads();
  }
  a0 += __shfl_xor(a0, 32);
  a1 += __shfl_xor(a1, 32);
  a2 += __shfl_xor(a2, 32);
  a3 += __shfl_xor(a3, 32);
  if (half == 0) {
    float4 bv = *(const float4*)(gb + sl * 4);
    a0 = sigm(a0 + bv.x); a1 = sigm(a1 + bv.y);
    a2 = sigm(a2 + bv.z); a3 = sigm(a3 + bv.w);
    uint2 o;
    o.x = ((u32)f2bf(a1) << 16) | (u32)f2bf(a0);
    o.y = ((u32)f2bf(a3) << 16) | (u32)f2bf(a2);
    *(uint2*)((char*)g + (((size_t)bid) << 8) + slB) = o;
  }
}

// ---------------- output projection: out = h1 @ ow + ob ----------------
__global__ void k_out(const u16* __restrict__ h, const float* __restrict__ ow,
                      const float* __restrict__ ob, float* __restrict__ out, int M) {
  __shared__ float lw[HDIM * OUTD];
  __shared__ float lb[OUTD];
  int tid = threadIdx.x;  // 256
  for (int i = tid; i < HDIM * OUTD; i += 256) lw[i] = ow[i];
  if (tid < OUTD) lb[tid] = ob[tid];
  __syncthreads();
  int j = tid & 63;
  int nl = tid >> 6;
  int n = blockIdx.x * 4 + nl;
  if (n >= M) return;
  const u16* hr = h + (size_t)n * HDIM;
  float s = lb[j];
#pragma unroll 4
  for (int k = 0; k < HDIM; ++k) s += bflo((u32)hr[k] << 0 ? (u32)hr[k] : (u32)hr[k]) * 0.f + __uint_as_float(((u32)hr[k]) << 16) * lw[k * OUTD + j];
  out[(size_t)n * OUTD + j] = s;
}

// ---------------- host ----------------
extern "C" void kernel_launch(void* const* d_in, const int* in_sizes, int n_in,
                              void* d_out, int out_size, void* d_ws, size_t ws_size,
                              hipStream_t stream) {
  const float* x  = (const float*)d_in[0];
  const float* ea = (const float*)d_in[1];
  const int*   ei = (const int*)d_in[2];
  const float* gw[2] = { (const float*)d_in[3],  (const float*)d_in[13] };
  const float* gb[2] = { (const float*)d_in[4],  (const float*)d_in[14] };
  const float* wg[2][4] = {
    { (const float*)d_in[5],  (const float*)d_in[7],  (const float*)d_in[9],  (const float*)d_in[11] },
    { (const float*)d_in[15], (const float*)d_in[17], (const float*)d_in[19], (const float*)d_in[21] } };
  const float* bg[2][4] = {
    { (const float*)d_in[6],  (const float*)d_in[8],  (const float*)d_in[10], (const float*)d_in[12] },
    { (const float*)d_in[16], (const float*)d_in[18], (const float*)d_in[20], (const float*)d_in[22] } };
  const float* ow = (const float*)d_in[23];
  const float* ob = (const float*)d_in[24];
  float* out = (float*)d_out;

  const int N = in_sizes[0] / (HDIM * TSTEPS);
  const int E = in_sizes[2] / 2;
  const int nh = N * HDIM;
  const int tnh = TSTEPS * nh;

  size_t off = 0;
  auto alloc = [&](size_t bytes) -> void* {
    void* p = (char*)d_ws + off;
    off += (bytes + 255) & ~(size_t)255;
    return p;
  };
  u16* xb     = (u16*)alloc((size_t)tnh * 2);
  u16* xw_all = (u16*)alloc((size_t)tnh * 2);
  u16* g0_all = (u16*)alloc((size_t)tnh * 2);
  u16* H0[3] = { (u16*)alloc((size_t)nh * 2), (u16*)alloc((size_t)nh * 2), (u16*)alloc((size_t)nh * 2) };
  u16* H1[2] = { (u16*)alloc((size_t)nh * 2), (u16*)alloc((size_t)nh * 2) };
  u16* g1buf = (u16*)alloc((size_t)nh * 2);
  u16* xw1[2] = { (u16*)alloc((size_t)nh * 2), (u16*)alloc((size_t)nh * 2) };
  float* cst[2] = { (float*)alloc((size_t)nh * 4), (float*)alloc((size_t)nh * 4) };
  float* dis   = (float*)alloc((size_t)N * 4);
  int* cnt     = (int*)alloc((size_t)N * 4);
  int* cursor  = (int*)alloc((size_t)N * 4);
  int* rp      = (int*)alloc((size_t)(N + 1) * 4);
  uint2* ee    = (uint2*)alloc((size_t)(E + N) * 8);
  u16* gwT[2] = { (u16*)alloc(HDIM * HDIM * 2), (u16*)alloc(HDIM * HDIM * 2) };
  u16* w4T[2] = { (u16*)alloc(512 * 384 * 2),   (u16*)alloc(512 * 384 * 2) };
  float* b4[2] = { (float*)alloc(512 * 4), (float*)alloc(512 * 4) };
  alloc(32768);  // slack so OOB tile reads (<=96 rows) stay mapped

  // setup
  k_init<<<(nh + 255) / 256, 256, 0, stream>>>(cst[0], cst[1], H0[2], H1[1], cnt, cursor, N);
  k_xpose<<<(nh + 255) / 256, 256, 0, stream>>>(x, xb, N);
  k_cnt<<<(E + 255) / 256, 256, 0, stream>>>(ei, cnt, E);
  k_scan<<<1, 1024, 0, stream>>>(cnt, rp, N);
  k_scatter<<<(E + 255) / 256, 256, 0, stream>>>(ei, ea, rp, cursor, ee, E);
  k_degcsr<<<N, 64, 0, stream>>>(rp, ee, dis, N);
  k_enrm<<<N, 64, 0, stream>>>(rp, dis, ee, N);
  for (int l = 0; l < 2; ++l) {
    k_wt<<<(HDIM * HDIM + 255) / 256, 256, 0, stream>>>(gw[l], gwT[l], HDIM, HDIM, HDIM);
    k_wt4<<<(512 * 384 + 255) / 256, 256, 0, stream>>>(wg[l][0], wg[l][1], wg[l][2], wg[l][3], w4T[l]);
    k_bias4<<<2, 256, 0, stream>>>(bg[l][0], bg[l][1], bg[l][2], bg[l][3], b4[l]);
  }

  const int nb = (N + 127) / 128;
  GA zga = { xb, xb, xb, w4T[0], b4[0], cst[0], H0[0] };  // placeholder (never used when ngate limits y)
  GJ zgj = { xb, gwT[0], xw_all };

  // batched layer-0 GCN linear: xw_all = xb @ gwT0 (all 12 timesteps)
  {
    int Mb = tnh / HDIM;
    GJ gj = { xb, gwT[0], xw_all };
    k_mega<<<dim3((Mb + 127) / 128, 1), 256, 0, stream>>>(zga, zga, gj, Mb, 0, N);
  }
  k_agg<<<TSTEPS * N, 64, 0, stream>>>(xw_all, rp, ee, gb[0], g0_all, N);

  // P0: gate0_0 (h0_{-1} = H0[2] zeros) -> H0[0]
  {
    GA a0 = { xb, g0_all, H0[2], w4T[0], b4[0], cst[0], H0[0] };
    k_mega<<<dim3(nb, 4), 256, 0, stream>>>(a0, a0, zgj, N, 1, N);
  }
  // P1: gcn1_0 (H0[0] -> xw1[0])  ||  gate0_1 -> H0[1]
  {
    GA a0 = { xb + (size_t)nh, g0_all + (size_t)nh, H0[0], w4T[0], b4[0], cst[0], H0[1] };
    GJ gj = { H0[0], gwT[1], xw1[0] };
    k_mega<<<dim3(nb, 5), 256, 0, stream>>>(a0, a0, gj, N, 1, N);
  }

  for (int t = 0; t < TSTEPS; ++t) {
    // A_t: aggregate layer-1 GCN for step t
    k_agg<<<N, 64, 0, stream>>>(xw1[t & 1], rp, ee, gb[1], g1buf, N);
    // B_t: gate1_t || gcn1_{t+1} || gate0_{t+2}
    GA a0 = { H0[t % 3], g1buf, H1[(t + 1) & 1], w4T[1], b4[1], cst[1], H1[t & 1] };
    int ngate = 1, hasg = 0;
    GA a1 = a0;
    GJ gj = zgj;
    if (t + 2 < TSTEPS) {
      a1 = GA{ xb + (size_t)(t + 2) * nh, g0_all + (size_t)(t + 2) * nh, H0[(t + 1) % 3],
               w4T[0], b4[0], cst[0], H0[(t + 2) % 3] };
      ngate = 2;
    }
    if (t + 1 < TSTEPS) {
      gj = GJ{ H0[(t + 1) % 3], gwT[1], xw1[(t + 1) & 1] };
      hasg = 1;
    }
    k_mega<<<dim3(nb, 4 * ngate + hasg), 256, 0, stream>>>(a0, a1, gj, N, ngate, N);
  }
  k_out<<<(N + 3) / 4, 256, 0, stream>>>(H1[1], ow, ob, out, N);
}